// Round 12
// baseline (307.901 us; speedup 1.0000x reference)
//
#include <hip/hip_runtime.h>
#include <stdint.h>

using short8   = __attribute__((ext_vector_type(8))) short;
using short4_  = __attribute__((ext_vector_type(4))) short;
using float4_  = __attribute__((ext_vector_type(4))) float;
using ushort4_ = __attribute__((ext_vector_type(4))) unsigned short;
typedef unsigned int  uint;
typedef unsigned short ushort;

// ---------- bf16 helpers ----------
__device__ __forceinline__ float bf2f(ushort b) {
  uint u = ((uint)b) << 16;
  return __builtin_bit_cast(float, u);
}
__device__ __forceinline__ ushort f2bf(float f) {
  uint u = __builtin_bit_cast(uint, f);
  u = u + 0x7fffu + ((u >> 16) & 1u);   // RTNE
  return (ushort)(u >> 16);
}
// raw 2^x
__device__ __forceinline__ float exp2_hw(float x) {
  float r;
  asm("v_exp_f32 %0, %1" : "=v"(r) : "v"(x));
  return r;
}
// async global->LDS 16B per lane (dest = uniform base + lane*16)
__device__ __forceinline__ void gld_lds16(const ushort* g, ushort* l) {
  __builtin_amdgcn_global_load_lds(
      (const __attribute__((address_space(1))) void*)g,
      (__attribute__((address_space(3))) void*)l, 16, 0, 0);
}
// inline dtype ballot: 1 = f32 inputs, 0 = bf16. All waves agree (same 64 words).
__device__ __forceinline__ int detect_f32(const uint* __restrict__ det) {
  int lane = threadIdx.x & 63;
  uint w = det[lane];
  ushort lo = (ushort)(w & 0xffffu);
  int e = (lo >> 7) & 0xff;
  int sane = (lo == 0 || (e >= 0x60 && e <= 0x9f)) ? 1 : 0;
  unsigned long long b = __ballot(sane);
  return (__popcll(b) >= 56) ? 0 : 1;
}
// raw weight read as bf16 (bitwise-identical to the converted arena value)
__device__ __forceinline__ ushort bfw(const void* p, int i, int fl) {
  return fl ? f2bf(((const float*)p)[i]) : ((const ushort*)p)[i];
}

#define LOG2E 1.4426950408889634f

// ---------- constants ----------
#define NN   216
#define NSQ  46656
#define PADV (-3.0e6f)

#if __has_builtin(__builtin_amdgcn_mfma_f32_16x16x16bf16_1k)
  #define HAVE_MFMA16 1
  #define MFMA16(a, b, c) __builtin_amdgcn_mfma_f32_16x16x16bf16_1k(a, b, c, 0, 0, 0)
#elif __has_builtin(__builtin_amdgcn_mfma_f32_16x16x16_bf16)
  #define HAVE_MFMA16 1
  #define MFMA16(a, b, c) __builtin_amdgcn_mfma_f32_16x16x16_bf16(a, b, c, 0, 0, 0)
#else
  #define HAVE_MFMA16 0
#endif

// weight arena element offsets
#define WA_WQKV   0
#define WA_BQKV   110592
#define WA_WPROJ  111168
#define WA_BPROJ  148032
#define WA_PPW    148224
#define WA_PPB    148260
#define WA_G1     148272
#define WA_B1     148284
#define WA_W1     148296
#define WA_WB1    148440
#define WA_G2     148452
#define WA_B2     148464
#define WA_W2     148476
#define WA_WB2    148620
#define WA_G3     148632
#define WA_B3     148644
#define WA_W3     148656
#define WA_WB3    148728
#define WA_TOTAL  148740

struct SrcPtrs { const void* p[18]; };
// sp.p index map: 0 Wqkv, 1 bqkv, 2 Wproj, 3 bproj, 4 PPW, 5 PPB,
// 6 G1, 7 B1, 8 W1, 9 WB1, 10 G2, 11 B2, 12 W2, 13 WB2,
// 14 G3, 15 B3, 16 W3, 17 WB3

// =====================================================================
// mega-pre kernel: convpack(78) + pos_mlp_raw(6) + packa(5184) +
// maskfrag(3136) = 8404 blocks. All parts depend ONLY on raw inputs
// (pos MLP reads raw weights with inline f2bf — bitwise-identical to
// reading the converted arena). Block bodies are byte-identical to
// the R7 standalone kernels.
// =====================================================================
__device__ __forceinline__ void ln_relu_raw(const float* p, const void* g,
                                            const void* b, int fl, float* r) {
  float m = 0.f;
#pragma unroll
  for (int t = 0; t < 12; ++t) m += p[t];
  m *= (1.f / 12.f);
  float v = 0.f;
#pragma unroll
  for (int t = 0; t < 12; ++t) { float d = p[t] - m; v += d * d; }
  v *= (1.f / 12.f);
  float inv = rsqrtf(v + 1e-5f);
#pragma unroll
  for (int t = 0; t < 12; ++t) {
    float z = (p[t] - m) * inv * bf2f(bfw(g, t, fl)) + bf2f(bfw(b, t, fl));
    r[t] = fmaxf(z, 0.f);
  }
}

__global__ __launch_bounds__(256) void mega_pre_kernel(
    SrcPtrs sp, const uint* __restrict__ xdet,
    const void* __restrict__ ysrc, const void* __restrict__ maskv,
    ushort* __restrict__ warena, ushort* __restrict__ wp,
    ushort* __restrict__ yf, ushort* __restrict__ maskf,
    float* __restrict__ pos) {
  int bid = blockIdx.x, tid = threadIdx.x;

  if (bid < 72) {
    // ---- packw from raw ----
    int fl = detect_f32(xdet);
    int c = bid * 256 + tid;
    int blob = c / 2304, s = c - blob * 2304;
    int kk = s / 384, r = s - kk * 384;
    int nt = r >> 6, l = r & 63;
    int l16 = l & 15, qd = l >> 4;
    int col; const void* src;
    if (blob < 6) { int z = blob >> 1, half = blob & 1;
                    col = z * 192 + half * 96 + nt * 16 + l16; src = sp.p[0]; }
    else          { col = (blob - 6) * 96 + nt * 16 + l16;     src = sp.p[2]; }
    size_t off = (size_t)col * 192 + kk * 32 + qd * 8;
    short8 pk;
    if (fl) {
      float4_ lo = *(const float4_*)((const float*)src + off);
      float4_ hi = *(const float4_*)((const float*)src + off + 4);
#pragma unroll
      for (int j = 0; j < 4; ++j) {
        pk[j]     = (short)f2bf(lo[j]);
        pk[4 + j] = (short)f2bf(hi[j]);
      }
    } else {
      pk = *(const short8*)((const ushort*)src + off);
    }
    *(short8*)(wp + (size_t)c * 8) = pk;

  } else if (bid < 78) {
    // ---- compact convert: BQKV (576) + [BPROJ..TOTAL) (708) ----
    int fl = detect_f32(xdet);
    constexpr int OFF[19] = {WA_WQKV, WA_BQKV, WA_WPROJ, WA_BPROJ, WA_PPW, WA_PPB,
                             WA_G1, WA_B1, WA_W1, WA_WB1, WA_G2, WA_B2, WA_W2,
                             WA_WB2, WA_G3, WA_B3, WA_W3, WA_WB3, WA_TOTAL};
    int u = (bid - 72) * 256 + tid;
    if (u >= 1284) return;
    int t, a;
    if (u < 576) { t = WA_BQKV + u; a = 1; }
    else {
      t = WA_BPROJ + (u - 576);
      a = 3;
#pragma unroll
      for (int i = 4; i < 18; ++i) a += (t >= OFF[i]) ? 1 : 0;
    }
    int local = t - OFF[a];
    const void* s = sp.p[a];
    warena[t] = fl ? f2bf(((const float*)s)[local]) : ((const ushort*)s)[local];

  } else if (bid < 84) {
    // ---- pos MLP from RAW weights (bitwise = converted-arena path) ----
    int fl = detect_f32(xdet);
    int m = (bid - 78) * 256 + tid;
    if (m >= 1331) return;
    int ih = m / 121, rem = m - ih * 121;
    int iw = rem / 11, id = rem - iw * 11;
    float fh = (float)(ih - 5), fw = (float)(iw - 5), fd = (float)(id - 5);
    float p[12], r[12], q[12];
#pragma unroll
    for (int t = 0; t < 12; ++t)
      p[t] = fh * bf2f(bfw(sp.p[4], t * 3, fl)) +
             fw * bf2f(bfw(sp.p[4], t * 3 + 1, fl)) +
             fd * bf2f(bfw(sp.p[4], t * 3 + 2, fl)) +
             bf2f(bfw(sp.p[5], t, fl));
    ln_relu_raw(p, sp.p[6], sp.p[7], fl, r);
#pragma unroll
    for (int t = 0; t < 12; ++t) {
      float s = bf2f(bfw(sp.p[9], t, fl));
#pragma unroll
      for (int u = 0; u < 12; ++u) s += r[u] * bf2f(bfw(sp.p[8], t * 12 + u, fl));
      q[t] = s;
    }
    ln_relu_raw(q, sp.p[10], sp.p[11], fl, r);
#pragma unroll
    for (int t = 0; t < 12; ++t) {
      float s = bf2f(bfw(sp.p[13], t, fl));
#pragma unroll
      for (int u = 0; u < 12; ++u) s += r[u] * bf2f(bfw(sp.p[12], t * 12 + u, fl));
      p[t] = s;
    }
    ln_relu_raw(p, sp.p[14], sp.p[15], fl, r);
#pragma unroll
    for (int hh = 0; hh < 6; ++hh) {
      float s = bf2f(bfw(sp.p[17], hh, fl));
#pragma unroll
      for (int u = 0; u < 12; ++u) s += r[u] * bf2f(bfw(sp.p[16], hh * 12 + u, fl));
      pos[m * 6 + hh] = s;
    }

  } else if (bid < 84 + 5184) {
    // ---- packa (y -> A-fragment-linear) ----
    int fl = detect_f32((const uint*)ysrc);
    int c = (bid - 84) * 256 + tid;
    int tile = c / 3072, cc = c - tile * 3072;
    int kk = cc / 512, c2 = cc - kk * 512;
    int rowhi = c2 / 64, c3 = c2 - rowhi * 64;
    int q = c3 >> 4, l16 = c3 & 15;
    size_t M = (size_t)tile * 128 + rowhi * 16 + l16;
    size_t so = M * 192 + kk * 32 + q * 8;
    short8 pk;
    if (fl) {
      float4_ lo = *(const float4_*)((const float*)ysrc + so);
      float4_ hi = *(const float4_*)((const float*)ysrc + so + 4);
#pragma unroll
      for (int j = 0; j < 4; ++j) {
        pk[j]     = (short)f2bf(lo[j]);
        pk[4 + j] = (short)f2bf(hi[j]);
      }
    } else {
      pk = *(const short8*)((const ushort*)ysrc + so);
    }
    *(short8*)(yf + (size_t)c * 8) = pk;

  } else {
    // ---- maskfrag ----
    bool mf32 = detect_f32(xdet) != 0;
    int tgl = (bid - 5268) * 256 + tid;
    int lane = tgl & 63;
    int tj   = (tgl >> 6) % 196;
    int g    = (tgl >> 6) / 196;
    int tt = tj / 14, jt = tj - tt * 14;
    int l16 = lane & 15, quad = lane >> 4;
    int i = tt * 16 + l16;
    int jbase = jt * 16 + quad * 4;
    ushort4_ o;
    if (i < 216 && jbase < 216) {
      int mi = i * 216 + jbase;
      if (mf32) {
        float4_ mv = *(const float4_*)((const float*)maskv + (size_t)g * NSQ + mi);
#pragma unroll
        for (int r = 0; r < 4; ++r) o[r] = f2bf(mv[r] * LOG2E);
      } else {
        ushort4_ raw = *(const ushort4_*)((const ushort*)maskv + (size_t)g * NSQ + mi);
#pragma unroll
        for (int r = 0; r < 4; ++r) o[r] = f2bf(bf2f(raw[r]) * LOG2E);
      }
    } else {
#pragma unroll
      for (int r = 0; r < 4; ++r) o[r] = f2bf(PADV);
    }
    *(ushort4_*)(maskf + (size_t)tgl * 4) = o;
  }
}

// =====================================================================
// shared GEMM body (R7 v5, unchanged math)
// =====================================================================
template<int NT, int IS_PROJ>
__device__ __forceinline__ void gemm_body(
    ushort* b_lds, int tile, int zz, int tid,
    const void* __restrict__ Arow, const ushort* __restrict__ Apack,
    const ushort* __restrict__ wpacked, const ushort* __restrict__ bias,
    void* __restrict__ dq, void* __restrict__ dk, void* __restrict__ dv,
    int fl) {
  int m0 = tile * 128;
  int n0   = IS_PROJ ? zz * 96 : 0;
  int blob = IS_PROJ ? (6 + zz) : (zz * 2);
  float scale = (!IS_PROJ && zz == 0) ? (0.17677669529663687f * LOG2E) : 1.0f;
  void* dst = IS_PROJ ? dq : (zz == 0 ? dq : (zz == 1 ? dk : dv));
  bool a_packed = (!IS_PROJ) && (zz != 0);
  bool f32path = (!IS_PROJ) && (zz == 0) && (fl != 0);
  bool o_f32 = IS_PROJ && (fl != 0);

  int lane = tid & 63, w = tid >> 6;
  int l16 = lane & 15, quad = lane >> 4;

  // ---- stage B first: async DMA, overlaps the A loads below ----
  {
    const ushort* wb = wpacked + (size_t)blob * 18432;
    int wuni = (tid >> 6) << 6;               // wave-uniform base chunk
#pragma unroll
    for (int it = 0; it < (NT * 3) / 2; ++it) {
      int base = wuni + it * 256;
      gld_lds16(wb + (size_t)(base + lane) * 8, b_lds + (size_t)base * 8);
    }
  }

  // ---- A fragments (M=128) ----
  short8 af[6][2];
  if (a_packed) {
    const ushort* tb = Apack + (size_t)tile * 24576 + lane * 8;
#pragma unroll
    for (int kk = 0; kk < 6; ++kk)
#pragma unroll
      for (int mt = 0; mt < 2; ++mt)
        af[kk][mt] = *(const short8*)(tb + kk * 4096 + (w * 2 + mt) * 512);
  } else if (f32path) {
#pragma unroll
    for (int kk = 0; kk < 6; ++kk)
#pragma unroll
      for (int mt = 0; mt < 2; ++mt) {
        const float* Af = (const float*)Arow +
            (size_t)(m0 + w * 32 + mt * 16 + l16) * 192 + kk * 32 + quad * 8;
        float4_ lo = *(const float4_*)Af;
        float4_ hi = *(const float4_*)(Af + 4);
#pragma unroll
        for (int j = 0; j < 4; ++j) {
          af[kk][mt][j]     = (short)f2bf(lo[j]);
          af[kk][mt][4 + j] = (short)f2bf(hi[j]);
        }
      }
  } else {
#pragma unroll
    for (int kk = 0; kk < 6; ++kk)
#pragma unroll
      for (int mt = 0; mt < 2; ++mt)
        af[kk][mt] = *(const short8*)((const ushort*)Arow +
            (size_t)(m0 + w * 32 + mt * 16 + l16) * 192 + kk * 32 + quad * 8);
  }
  __syncthreads();   // drains vmcnt (DMA + A loads)

  float4_ acc[2][NT];
#pragma unroll
  for (int mt = 0; mt < 2; ++mt)
#pragma unroll
    for (int nt = 0; nt < NT; ++nt) acc[mt][nt] = (float4_){0.f, 0.f, 0.f, 0.f};

#pragma unroll
  for (int kk = 0; kk < 6; ++kk) {
    short8 bfr[NT];
#pragma unroll
    for (int nt = 0; nt < NT; ++nt) {
      int halfb = nt / 6, nl = nt % 6;
      bfr[nt] = *(const short8*)(b_lds + halfb * 18432 + ((kk * 6 + nl) * 64 + lane) * 8);
    }
#pragma unroll
    for (int mt = 0; mt < 2; ++mt)
#pragma unroll
      for (int nt = 0; nt < NT; ++nt)
        acc[mt][nt] = __builtin_amdgcn_mfma_f32_16x16x32_bf16(af[kk][mt], bfr[nt], acc[mt][nt], 0, 0, 0);
  }

#pragma unroll
  for (int mt = 0; mt < 2; ++mt) {
#pragma unroll
    for (int nt = 0; nt < NT; ++nt) {
      int lcol = n0 + nt * 16 + l16;
      float bv = bf2f(bias[(IS_PROJ ? 0 : zz * 192) + lcol]);
#pragma unroll
      for (int r = 0; r < 4; ++r) {
        int grow = m0 + w * 32 + mt * 16 + quad * 4 + r;
        float val = (acc[mt][nt][r] + bv) * scale;
        if (IS_PROJ) {
          if (o_f32) ((float*)dst)[(size_t)grow * 192 + lcol] = val;
          else       ((ushort*)dst)[(size_t)grow * 192 + lcol] = f2bf(val);
        } else {
          int bb = grow / 216;
          int nn2 = grow - bb * 216;
          int hh = lcol >> 5, dd = lcol & 31;
          ((ushort*)dst)[(((size_t)bb * 6 + hh) * 216 + nn2) * 32 + dd] = f2bf(val);
        }
      }
    }
  }
}

// =====================================================================
// megaB: QKV gemm (1296 flattened blocks) + rpbfrag (294 blocks).
// Both depend only on mega_pre outputs.
// =====================================================================
__global__ __launch_bounds__(256, 2) void qkvrpb_kernel(
    const void* __restrict__ Ax, const ushort* __restrict__ Apack,
    const ushort* __restrict__ wpacked, const ushort* __restrict__ bias,
    void* __restrict__ dq, void* __restrict__ dk, void* __restrict__ dv,
    const uint* __restrict__ det,
    const float* __restrict__ pos, ushort* __restrict__ rpbf) {
  __shared__ __align__(16) ushort b_lds[12 * 3072];
  int bid = blockIdx.x;
  if (bid < 1296) {
    int fl = detect_f32(det);
    gemm_body<12, 0>(b_lds, bid % 432, bid / 432, threadIdx.x,
                     Ax, Apack, wpacked, bias, dq, dk, dv, fl);
  } else {
    int tgl = (bid - 1296) * 256 + threadIdx.x;
    int lane = tgl & 63;
    int tj   = (tgl >> 6) % 196;
    int h    = (tgl >> 6) / 196;
    int tt = tj / 14, jt = tj - tt * 14;
    int l16 = lane & 15, quad = lane >> 4;
    int i = tt * 16 + l16;
    int jbase = jt * 16 + quad * 4;
    ushort4_ o;
    if (i < 216 && jbase < 216) {
      int h1 = i / 36, r1 = i - h1 * 36, w1 = r1 / 6, d1 = r1 - w1 * 6;
#pragma unroll
      for (int r = 0; r < 4; ++r) {
        int j = jbase + r;
        int h2 = j / 36, r2 = j - h2 * 36, w2 = r2 / 6, d2 = r2 - w2 * 6;
        int idx = ((h1 - h2 + 5) * 11 + (w1 - w2 + 5)) * 11 + (d1 - d2 + 5);
        o[r] = f2bf(pos[idx * 6 + h] * LOG2E);
      }
    } else {
#pragma unroll
      for (int r = 0; r < 4; ++r) o[r] = f2bf(PADV);
    }
    *(ushort4_*)(rpbf + (size_t)tgl * 4) = o;
  }
}

// proj gemm keeps its own 2D launch
template<int NT, int IS_PROJ>
__global__ __launch_bounds__(256, 2) void gemm_kernel(
    const void* __restrict__ Arow, const ushort* __restrict__ Apack,
    const ushort* __restrict__ wpacked, const ushort* __restrict__ bias,
    void* __restrict__ dq, void* __restrict__ dk, void* __restrict__ dv,
    const uint* __restrict__ det) {
  __shared__ __align__(16) ushort b_lds[NT * 3072];
  int fl = detect_f32(det);
  gemm_body<NT, IS_PROJ>(b_lds, blockIdx.x, blockIdx.y, threadIdx.x,
                         Arow, Apack, wpacked, bias, dq, dk, dv, fl);
}

// =====================================================================
// 4) fused attention — R11 verbatim (setprio kept; neutral-to-helpful)
// =====================================================================
__global__ __launch_bounds__(448) void attn_kernel(
    const ushort* __restrict__ q, const ushort* __restrict__ k,
    const ushort* __restrict__ v, const ushort* __restrict__ rpbf,
    const ushort* __restrict__ maskf, ushort* __restrict__ opre) {
#if HAVE_MFMA16
  __shared__ __align__(16) ushort vfrag[28 * 64 * 4];
#else
  __shared__ __align__(16) ushort vfrag[14 * 64 * 8];
#endif

  // remap so the 24 blocks sharing mask group g are contiguous in dispatch
  int bid = blockIdx.x;
  int g   = bid / 24;
  int rr  = bid - g * 24;
  int bhi = rr / 6;
  int h   = rr - bhi * 6;
  int b   = bhi * 64 + g;

  int tid = threadIdx.x, lane = tid & 63, w = tid >> 6;   // w in [0,7)
  int l16 = lane & 15, quad = lane >> 4;

  const ushort* qh = q + (size_t)(b * 6 + h) * 6912;
  const ushort* kh = k + (size_t)(b * 6 + h) * 6912;
  const ushort* vh = v + (size_t)(b * 6 + h) * 6912;

#if HAVE_MFMA16
  for (int pos = tid; pos < 1792; pos += 448) {
    int chunk = pos >> 6, l = pos & 63;
    int kt = chunk >> 1, dh = chunk & 1;
    int qd = l >> 4, lv = l & 15;
    ushort4_ tmp;
#pragma unroll
    for (int j = 0; j < 4; ++j)
      tmp[j] = vh[(kt * 16 + qd * 4 + j) * 32 + dh * 16 + lv];
    *(ushort4_*)(vfrag + pos * 4) = tmp;
  }
#else
  for (int pos = tid; pos < 896; pos += 448) {
    int chunk = pos >> 6, l = pos & 63;
    int kt2 = chunk >> 1, dh = chunk & 1;
    int qd = l >> 4, lv = l & 15;
    short8 tmp;
#pragma unroll
    for (int j = 0; j < 8; ++j)
      tmp[j] = (short)vh[(kt2 * 32 + qd * 8 + j) * 32 + dh * 16 + lv];
    *(short8*)(vfrag + pos * 8) = tmp;
  }
#endif
  __syncthreads();

  for (int t = w; t < 14; t += 7) {
    int r0 = t * 16;
    const ushort* rf = rpbf  + ((size_t)(h * 196 + t * 14) * 64 + lane) * 4;
    const ushort* mf = maskf + ((size_t)(g * 196 + t * 14) * 64 + lane) * 4;
    short8 aq = *(const short8*)(qh + (r0 + l16) * 32 + quad * 8);

    float4_ st[14];
    __builtin_amdgcn_s_setprio(1);
#pragma unroll
    for (int jt = 0; jt < 14; ++jt) {
      ushort4_ rb = *(const ushort4_*)(rf + jt * 256);
      ushort4_ mb = *(const ushort4_*)(mf + jt * 256);
      float4_ cin;
#pragma unroll
      for (int r = 0; r < 4; ++r) cin[r] = bf2f(rb[r]) + bf2f(mb[r]);
      short8 bk = *(const short8*)(kh + (jt * 16 + l16) * 32 + quad * 8);
      st[jt] = __builtin_amdgcn_mfma_f32_16x16x32_bf16(bk, aq, cin, 0, 0, 0);
    }
    __builtin_amdgcn_s_setprio(0);

    float mx = -1e30f;
#pragma unroll
    for (int jt = 0; jt < 14; ++jt)
      mx = fmaxf(fmaxf(st[jt][0], st[jt][1]),
                 fmaxf(fmaxf(st[jt][2], st[jt][3]), mx));   // -> v_max3
    mx = fmaxf(mx, __shfl_xor(mx, 16));
    mx = fmaxf(mx, __shfl_xor(mx, 32));
    float sum = 0.f;
#pragma unroll
    for (int jt = 0; jt < 14; ++jt)
#pragma unroll
      for (int r = 0; r < 4; ++r) {
        float pe = exp2_hw(st[jt][r] - mx);   // logits already * log2e
        st[jt][r] = pe;
        sum += pe;
      }
    sum += __shfl_xor(sum, 16);
    sum += __shfl_xor(sum, 32);
    float inv = 1.0f / sum;

    float4_ o0 = (float4_){0.f, 0.f, 0.f, 0.f};
    float4_ o1 = (float4_){0.f, 0.f, 0.f, 0.f};

    __builtin_amdgcn_s_setprio(1);
#if HAVE_MFMA16
#pragma unroll
    for (int kt = 0; kt < 14; ++kt) {
      short4_ pa;
#pragma unroll
      for (int r = 0; r < 4; ++r) pa[r] = (short)f2bf(st[kt][r]);
      short4_ vb0 = *(const short4_*)(vfrag + ((kt * 2 + 0) * 64 + lane) * 4);
      short4_ vb1 = *(const short4_*)(vfrag + ((kt * 2 + 1) * 64 + lane) * 4);
      o0 = MFMA16(pa, vb0, o0);
      o1 = MFMA16(pa, vb1, o1);
    }
#else
#pragma unroll
    for (int kt2 = 0; kt2 < 7; ++kt2) {
      uint pe0 = ((uint)f2bf(st[2*kt2][0])) | (((uint)f2bf(st[2*kt2][1])) << 16);
      uint pe1 = ((uint)f2bf(st[2*kt2][2])) | (((uint)f2bf(st[2*kt2][3])) << 16);
      uint po0 = ((uint)f2bf(st[2*kt2+1][0])) | (((uint)f2bf(st[2*kt2+1][1])) << 16);
      uint po1 = ((uint)f2bf(st[2*kt2+1][2])) | (((uint)f2bf(st[2*kt2+1][3])) << 16);
      int slo = (((2 * quad) & 3) << 4) | l16;
      int shi = (((2 * quad + 1) & 3) << 4) | l16;
      uint e_lo0 = __shfl((int)pe0, slo), e_lo1 = __shfl((int)pe1, slo);
      uint o_lo0 = __shfl((int)po0, slo), o_lo1 = __shfl((int)po1, slo);
      uint e_hi0 = __shfl((int)pe0, shi), e_hi1 = __shfl((int)pe1, shi);
      uint o_hi0 = __shfl((int)po0, shi), o_hi1 = __shfl((int)po1, shi);
      uint lo0 = (quad < 2) ? e_lo0 : o_lo0, lo1 = (quad < 2) ? e_lo1 : o_lo1;
      uint hi0 = (quad < 2) ? e_hi0 : o_hi0, hi1 = (quad < 2) ? e_hi1 : o_hi1;
      uint4 paw = {lo0, lo1, hi0, hi1};
      short8 pa = __builtin_bit_cast(short8, paw);
      short8 vb0 = *(const short8*)(vfrag + ((kt2 * 2 + 0) * 64 + lane) * 8);
      short8 vb1 = *(const short8*)(vfrag + ((kt2 * 2 + 1) * 64 + lane) * 8);
      o0 = __builtin_amdgcn_mfma_f32_16x16x32_bf16(pa, vb0, o0, 0, 0, 0);
      o1 = __builtin_amdgcn_mfma_f32_16x16x32_bf16(pa, vb1, o1, 0, 0, 0);
    }
#endif
    __builtin_amdgcn_s_setprio(0);

#pragma unroll
    for (int r = 0; r < 4; ++r) {
      float ir = __shfl(inv, quad * 4 + r);
      int i = r0 + quad * 4 + r;
      if (i < 216) {
        size_t base = ((size_t)b * 216 + i) * 192 + h * 32;
        opre[base + l16]      = f2bf(o0[r] * ir);
        opre[base + 16 + l16] = f2bf(o1[r] * ir);
      }
    }
  }
}

// =====================================================================
// launch — 4 kernels (was 8): dependency-safe block-range unions.
//   1. mega_pre  = convpack + pos_mlp(raw) + packa + maskfrag
//   2. qkvrpb    = QKV gemm + rpbfrag
//   3. attn
//   4. proj gemm
// =====================================================================
extern "C" void kernel_launch(void* const* d_in, const int* in_sizes, int n_in,
                              void* d_out, int out_size, void* d_ws, size_t ws_size,
                              hipStream_t stream) {
  (void)in_sizes; (void)n_in; (void)out_size; (void)ws_size;

  char* p = (char*)d_ws;
  p += 256;                                   // (former flag slot, unused)
  ushort* warena  = (ushort*)p;        p += 298240;
  ushort* wpacked = (ushort*)p;        p += 294912;
  float*  pos     = (float*)p;         p += 32768;
  ushort* rpbf    = (ushort*)p;        p += 602112;
  ushort* maskf   = (ushort*)p;        p += 6422528;
  ushort* yf      = (ushort*)p;        p += 21234688;  // aliased as opre after QKV GEMM
  ushort* qb      = (ushort*)p;        p += 21234688;
  ushort* kb      = (ushort*)p;        p += 21234688;
  ushort* vb      = (ushort*)p;
  ushort* opre    = yf;

  const uint* xdet = (const uint*)d_in[0];

  SrcPtrs sp;
  for (int i = 0; i < 18; ++i) sp.p[i] = d_in[3 + i];

  mega_pre_kernel<<<8404, 256, 0, stream>>>(
      sp, xdet, d_in[1], d_in[2], warena, wpacked, yf, maskf, pos);

  qkvrpb_kernel<<<1590, 256, 0, stream>>>(
      d_in[0], yf, wpacked, warena + WA_BQKV, qb, kb, vb, xdet, pos, rpbf);

  attn_kernel<<<1536, 448, 0, stream>>>(qb, kb, vb, rpbf, maskf, opre);

  gemm_kernel<6, 1><<<dim3(432, 2), 256, 0, stream>>>(
      opre, nullptr, wpacked, warena + WA_BPROJ,
      d_out, d_out, d_out, xdet);
}